// Round 11
// baseline (856.508 us; speedup 1.0000x reference)
//
#include <hip/hip_runtime.h>

#define HIDDEN 4096
#define NKV 8
#define NH 32
#define HD 128
#define BATCH 2
#define SEQ 4096
#define ROWS (BATCH*SEQ)   // 8192

typedef short bf16x8 __attribute__((ext_vector_type(8)));
typedef float f32x4 __attribute__((ext_vector_type(4)));

static __device__ __forceinline__ float bf2f(unsigned short u) {
    union { unsigned int i; float f; } c; c.i = ((unsigned int)u) << 16; return c.f;
}
static __device__ __forceinline__ unsigned short f2bf(float x) {
    union { float f; unsigned int i; } c; c.f = x;
    unsigned int r = c.i + 0x7fffu + ((c.i >> 16) & 1u);
    return (unsigned short)(r >> 16);
}

static __device__ __forceinline__ void gl2lds16(const void* g, void* l) {
    __builtin_amdgcn_global_load_lds(
        (const __attribute__((address_space(1))) unsigned int*)g,
        (__attribute__((address_space(3))) unsigned int*)l, 16, 0, 0);
}

#define WGBAR() __builtin_amdgcn_s_barrier()
#define VMW(n) asm volatile("s_waitcnt vmcnt(" #n ")" ::: "memory")
#define LGKMS(s) asm volatile("s_waitcnt lgkmcnt(" s ")" ::: "memory")
#define SCHED_FENCE() __builtin_amdgcn_sched_barrier(0)
#define MFMA_(a,b,c) __builtin_amdgcn_mfma_f32_16x16x32_bf16((a),(b),(c),0,0,0)

// ---------------------------------------------------------------- casts
__global__ __launch_bounds__(256)
void cast_kernel(const float* __restrict__ in, unsigned short* __restrict__ out, int n4) {
    int idx = blockIdx.x * blockDim.x + threadIdx.x;
    int stride = gridDim.x * blockDim.x;
    for (int i = idx; i < n4; i += stride) {
        float4 f = ((const float4*)in)[i];
        ushort4 o;
        o.x = f2bf(f.x); o.y = f2bf(f.y); o.z = f2bf(f.z); o.w = f2bf(f.w);
        ((ushort4*)out)[i] = o;
    }
}

// ---------------------------------------------------------------- 256x256 GEMM, BK=32, distance-2 + cross-tile read-ahead.
// 4 LDS bufs x 32KB. Tile t: stage t+2 at top; compute t from PRE-READ regs
// (B x4 + A mp0,1) filled during tile t-1; own reads (A mp2..7) + next-tile
// pre-reads issued BETWEEN MFMA clusters (LDS overlaps MFMA); VMW(0)+barrier
// at end (drain is free: 1-tile cover; ZERO vmem in flight across barriers).
// lgkm invariant: exactly 6 own pre-reads carried across each barrier.
// LDS panel layout: [r%128][128B], inner = ((r/128)<<6 | k*2) ^ ((r&7)<<4).
// K must be 4096 (NT=128 tiles, unroll 4: 31 full iters + 4-tile tail).
// MODE 0: f32 out, +bias0
// MODE 1: bf16 out, phi(x + bias0)          (Q projection)
// MODE 2: bf16 out, col<1024: phi(x+bias0[col]) else x+bias1[col-1024]  (fused KV)
template<int MODE>
__global__ __launch_bounds__(512, 2)
void gemm256(const unsigned short* __restrict__ A, int lda,
             const unsigned short* __restrict__ B, int ldb,
             const float* __restrict__ bias0, const float* __restrict__ bias1,
             void* __restrict__ Cout, int M, int N, int K)
{
    __shared__ __align__(16) unsigned char sm[131072];   // 4 x (A 16KB + B 16KB)

    const int tid = threadIdx.x;
    const int wid = tid >> 6, lane = tid & 63;
    const int wr = wid >> 2, wc = wid & 3;           // wave grid 2M x 4N
    const int lr = lane & 15, kg = lane >> 4;
    const int swz = (lane & 7) << 4;

    // XCD-aware block swizzle (nwg % 8 == 0 for all launches here)
    int nbx = N >> 8;
    int nwg = nbx * (M >> 8);
    int cpx = nwg >> 3;
    int bid = (int)blockIdx.x;
    int wg = (bid & 7) * cpx + (bid >> 3);
    int bx = wg % nbx, by = wg / nbx;
    int rowBase = by << 8, colBase = bx << 8;

    // staging source offsets: invert layout at linear dest o = i*8192+tid*16
    size_t sA[2], sB[2];
#pragma unroll
    for (int i = 0; i < 2; ++i) {
        int o = i * 8192 + tid * 16;
        int rm = o >> 7;
        int inner = (o & 127) ^ ((rm & 7) << 4);
        int half = inner >> 6;
        int ke = (inner & 63) >> 1;
        sA[i] = (size_t)(rowBase + half * 128 + rm) * lda + ke;
        sB[i] = (size_t)(colBase + half * 128 + rm) * ldb + ke;
    }
    const int ldsW = wid * 1024;

    auto STAGE = [&](int nb, size_t ko) {
        gl2lds16(A + sA[0] + ko, sm + nb + 0 * 8192 + ldsW);
        gl2lds16(A + sA[1] + ko, sm + nb + 1 * 8192 + ldsW);
        gl2lds16(B + sB[0] + ko, sm + nb + 16384 + 0 * 8192 + ldsW);
        gl2lds16(B + sB[1] + ko, sm + nb + 16384 + 1 * 8192 + ldsW);
    };

    const int aRd = (lr << 7) + ((((wr << 6) | (kg << 4))) ^ swz);
    const int bRd = 16384 + ((((wc & 1) * 64 + lr)) << 7)
                  + (((((wc >> 1) << 6) | (kg << 4))) ^ swz);

    auto RA = [&](int cb, int mp) -> bf16x8 {
        return *(const bf16x8*)(sm + cb + aRd + mp * 2048);
    };
    auto RB = [&](int cb, int n) -> bf16x8 {
        return *(const bf16x8*)(sm + cb + bRd + n * 2048);
    };

    f32x4 acc[8][4] = {};

// MFMA cluster on C-rows M0,M1 with B regs B0..B3 (all literal-indexed)
#define MFC(B0,B1,B2,B3, X0, X1, M0, M1) \
    { SCHED_FENCE(); \
      __builtin_amdgcn_s_setprio(1); \
      acc[M0][0]=MFMA_(X0,B0,acc[M0][0]); acc[M1][0]=MFMA_(X1,B0,acc[M1][0]); \
      acc[M0][1]=MFMA_(X0,B1,acc[M0][1]); acc[M1][1]=MFMA_(X1,B1,acc[M1][1]); \
      acc[M0][2]=MFMA_(X0,B2,acc[M0][2]); acc[M1][2]=MFMA_(X1,B2,acc[M1][2]); \
      acc[M0][3]=MFMA_(X0,B3,acc[M0][3]); acc[M1][3]=MFMA_(X1,B3,acc[M1][3]); \
      __builtin_amdgcn_s_setprio(0); }

// One K-tile. Entry lgkm outstanding = 6 (pre-reads BC*,AC* issued last tile).
// L2/L3: "6","6" when DO_PRE=1 (pre-reads in flight), "2","0" for final tile.
#define TILE_STEP(CB, NB, SB, BC0,BC1,BC2,BC3, AC0, AC1, BN0,BN1,BN2,BN3, AN0, AN1, DO_STAGE, DO_PRE, KO, L2, L3) \
    { \
        SCHED_FENCE(); \
        if (DO_STAGE) { STAGE((SB), (KO)); } \
        SCHED_FENCE(); \
        bf16x8 t2a = RA((CB),2), t2b = RA((CB),3); \
        SCHED_FENCE(); \
        LGKMS("2");                 /* drain the 6 pre-reads; G2 in flight */ \
        MFC(BC0,BC1,BC2,BC3, AC0, AC1, 0, 1); \
        bf16x8 t3a = RA((CB),4), t3b = RA((CB),5); \
        SCHED_FENCE(); \
        LGKMS("2");                 /* G2 done; G3 in flight */ \
        MFC(BC0,BC1,BC2,BC3, t2a, t2b, 2, 3); \
        bf16x8 t4a = RA((CB),6), t4b = RA((CB),7); \
        SCHED_FENCE(); \
        if (DO_PRE) { BN0=RB((NB),0); BN1=RB((NB),1); BN2=RB((NB),2); BN3=RB((NB),3); } \
        SCHED_FENCE(); \
        LGKMS(L2);                  /* G3 done; G4(+preB) in flight */ \
        MFC(BC0,BC1,BC2,BC3, t3a, t3b, 4, 5); \
        if (DO_PRE) { AN0 = RA((NB),0); AN1 = RA((NB),1); } \
        SCHED_FENCE(); \
        LGKMS(L3);                  /* G4 done; pre-reads (6) in flight */ \
        MFC(BC0,BC1,BC2,BC3, t4a, t4b, 6, 7); \
        VMW(0);                     /* free: stages issued a full tile ago */ \
        WGBAR(); \
        SCHED_FENCE(); \
    }

    bf16x8 bX0, bX1, bX2, bX3, aX0, aX1;   // set X: even tiles
    bf16x8 bY0, bY1, bY2, bY3, aY0, aY1;   // set Y: odd tiles

    // prologue: stage tiles 0,1; publish; pre-read tile 0 into set X (6 reads)
    SCHED_FENCE();
    STAGE(0, 0);
    STAGE(32768, 32);
    SCHED_FENCE();
    VMW(0);
    WGBAR();
    SCHED_FENCE();
    bX0 = RB(0, 0); bX1 = RB(0, 1); bX2 = RB(0, 2); bX3 = RB(0, 3);
    aX0 = RA(0, 0); aX1 = RA(0, 1);
    SCHED_FENCE();

    // main loop: 31 iterations x 4 tiles (tiles 0..123); K assumed 4096 (NT=128)
    size_t kb = 64;                 // tile t stages tile t+2 -> ko=(t+2)*32
    for (int it = 0; it < 31; ++it) {
        TILE_STEP(0,     32768, 65536, bX0,bX1,bX2,bX3, aX0, aX1, bY0,bY1,bY2,bY3, aY0, aY1, 1, 1, kb,      "6", "6");
        TILE_STEP(32768, 65536, 98304, bY0,bY1,bY2,bY3, aY0, aY1, bX0,bX1,bX2,bX3, aX0, aX1, 1, 1, kb + 32, "6", "6");
        TILE_STEP(65536, 98304, 0,     bX0,bX1,bX2,bX3, aX0, aX1, bY0,bY1,bY2,bY3, aY0, aY1, 1, 1, kb + 64, "6", "6");
        TILE_STEP(98304, 0,     32768, bY0,bY1,bY2,bY3, aY0, aY1, bX0,bX1,bX2,bX3, aX0, aX1, 1, 1, kb + 96, "6", "6");
        kb += 128;
    }
    // tail: tiles 124..127 (kb == 4032 here)
    TILE_STEP(0,     32768, 65536, bX0,bX1,bX2,bX3, aX0, aX1, bY0,bY1,bY2,bY3, aY0, aY1, 1, 1, 4032, "6", "6");
    TILE_STEP(32768, 65536, 98304, bY0,bY1,bY2,bY3, aY0, aY1, bX0,bX1,bX2,bX3, aX0, aX1, 1, 1, 4064, "6", "6");
    TILE_STEP(65536, 98304, 0,     bX0,bX1,bX2,bX3, aX0, aX1, bY0,bY1,bY2,bY3, aY0, aY1, 0, 1, 0,    "6", "6");
    TILE_STEP(98304, 0,     0,     bY0,bY1,bY2,bY3, aY0, aY1, bX0,bX1,bX2,bX3, aX0, aX1, 0, 0, 0,    "2", "0");

#undef TILE_STEP
#undef MFC

    // ---- C write
    int r0 = rowBase + wr * 128 + kg * 4;
    int c0 = colBase + wc * 64 + lr;
#pragma unroll
    for (int n = 0; n < 4; ++n) {
        int col = c0 + n * 16;
        float bv;
        if (MODE == 2) bv = (col < 1024) ? bias0[col] : bias1[col - 1024];
        else           bv = bias0[col];
#pragma unroll
        for (int m = 0; m < 8; ++m) {
            int row = r0 + m * 16;
#pragma unroll
            for (int r = 0; r < 4; ++r) {
                float v = acc[m][n][r] + bv;
                if (MODE == 1) v = (v > 0.f) ? v + 1.f : __expf(v);
                if (MODE == 2 && col < 1024) v = (v > 0.f) ? v + 1.f : __expf(v);
                if (MODE == 0) ((float*)Cout)[(size_t)(row + r) * N + col] = v;
                else ((unsigned short*)Cout)[(size_t)(row + r) * N + col] = f2bf(v);
            }
        }
    }
}

// ---------------------------------------------------------------- kv partial: kv[c][d] += v[l,c]*k[l,d] over an L-chunk
__global__ __launch_bounds__(256)
void kv_partial(const unsigned short* __restrict__ Kb, const unsigned short* __restrict__ Vb,
                int ld, float* __restrict__ kvp, float* __restrict__ ksp)
{
    int chunk = blockIdx.x;   // 0..31 (128 rows each)
    int g = blockIdx.y;       // 0..15 = b*8+hkv
    int b = g >> 3, hkv = g & 7;
    __shared__ float kl[32][128];
    __shared__ float vl[32][128];
    int tid = threadIdx.x;
    int c0 = (tid >> 4) * 8, d0 = (tid & 15) * 8;
    float acc[8][8] = {};
    float ksacc = 0.0f;
    size_t rowBase = (size_t)b * SEQ + (size_t)chunk * 128;

    for (int sch = 0; sch < 4; ++sch) {
        __syncthreads();
        for (int t = tid; t < 512; t += 256) {
            int l = t >> 4, col = (t & 15) * 8;
            size_t off = (rowBase + sch * 32 + l) * ld + hkv * HD + col;
            uint4 kr = *(const uint4*)(Kb + off);
            uint4 vr = *(const uint4*)(Vb + off);
            unsigned int ku[4] = {kr.x, kr.y, kr.z, kr.w};
            unsigned int vu[4] = {vr.x, vr.y, vr.z, vr.w};
#pragma unroll
            for (int q = 0; q < 4; ++q) {
                kl[l][col + q * 2]     = bf2f((unsigned short)(ku[q] & 0xffff));
                kl[l][col + q * 2 + 1] = bf2f((unsigned short)(ku[q] >> 16));
                vl[l][col + q * 2]     = bf2f((unsigned short)(vu[q] & 0xffff));
                vl[l][col + q * 2 + 1] = bf2f((unsigned short)(vu[q] >> 16));
            }
        }
        __syncthreads();
        for (int l = 0; l < 32; ++l) {
            float vv[8], kk[8];
#pragma unroll
            for (int x = 0; x < 8; ++x) { vv[x] = vl[l][c0 + x]; kk[x] = kl[l][d0 + x]; }
#pragma unroll
            for (int x = 0; x < 8; ++x)
#pragma unroll
                for (int y = 0; y < 8; ++y)
                    acc[x][y] += vv[x] * kk[y];
        }
        if (tid < 128) {
            for (int l = 0; l < 32; ++l) ksacc += kl[l][tid];
        }
    }
    float* out = kvp + ((size_t)g * 32 + chunk) * (HD * HD);
#pragma unroll
    for (int x = 0; x < 8; ++x)
#pragma unroll
        for (int y = 0; y < 8; ++y)
            out[(c0 + x) * HD + d0 + y] = acc[x][y];
    if (tid < 128) ksp[((size_t)g * 32 + chunk) * HD + tid] = ksacc;
}

// ---------------------------------------------------------------- reduce partials -> kv_bf16, ksum
__global__ __launch_bounds__(256)
void kv_reduce(const float* __restrict__ kvp, const float* __restrict__ ksp,
               unsigned short* __restrict__ kvb, float* __restrict__ ksum)
{
    int slice = blockIdx.x;  // 0..15
    int g = blockIdx.y;      // 0..15
    int tid = threadIdx.x;
    int e = slice * 1024 + tid * 4;
    float4 s = {0.f, 0.f, 0.f, 0.f};
    for (int ch = 0; ch < 32; ++ch) {
        float4 p = *(const float4*)(kvp + ((size_t)g * 32 + ch) * (HD * HD) + e);
        s.x += p.x; s.y += p.y; s.z += p.z; s.w += p.w;
    }
    ushort4 o;
    o.x = f2bf(s.x); o.y = f2bf(s.y); o.z = f2bf(s.z); o.w = f2bf(s.w);
    *(ushort4*)(kvb + (size_t)g * HD * HD + e) = o;
    if (slice == 0 && tid < 128) {
        float ss = 0.f;
        for (int ch = 0; ch < 32; ++ch) ss += ksp[((size_t)g * 32 + ch) * HD + tid];
        ksum[g * HD + tid] = ss;
    }
}

// ---------------------------------------------------------------- attn GEMM: per (row-tile, head): C = q @ kv^T, /(ksum+eps), bf16 out
__global__ __launch_bounds__(256)
void attn_gemm(const unsigned short* __restrict__ Q,
               const unsigned short* __restrict__ KV,
               const float* __restrict__ KS,
               unsigned short* __restrict__ Out)
{
    const int BK = 32;
    __shared__ unsigned short As[128 * BK];
    __shared__ unsigned short Bs[128 * BK];

    int rt = blockIdx.x;   // 0..63
    int h  = blockIdx.y;   // 0..31
    int g = (rt >> 5) * NKV + (h >> 2);
    int rowBase = rt << 7;

    const unsigned short* A = Q + (size_t)h * HD;           // lda = HIDDEN
    const unsigned short* B = KV + (size_t)g * HD * HD;     // ldb = HD
    const float* ks = KS + g * HD;

    int tid = threadIdx.x;
    int wave = tid >> 6, lane = tid & 63;
    int wr = wave >> 1, wc = wave & 1;

    f32x4 acc[4][4] = {};

    int sr = lane >> 2;
    int sc = (lane & 3) * 8;

    const unsigned short* Aw = A + (size_t)(rowBase + wave * 32 + sr) * HIDDEN + sc;
    const unsigned short* Bw = B + (size_t)(wave * 32 + sr) * HD + sc;
    unsigned short* Asw = As + wave * 32 * BK;
    unsigned short* Bsw = Bs + wave * 32 * BK;

    int arow = (wr * 64 + (lane & 15)) * BK + (lane >> 4) * 8;
    int brow = (wc * 64 + (lane & 15)) * BK + (lane >> 4) * 8;

    for (int kt = 0; kt < HD; kt += BK) {
        gl2lds16(Aw + kt, Asw);
        gl2lds16(Aw + kt + (size_t)16 * HIDDEN, Asw + 16 * BK);
        gl2lds16(Bw + kt, Bsw);
        gl2lds16(Bw + kt + (size_t)16 * HD, Bsw + 16 * BK);
        __syncthreads();
        bf16x8 af[4], bfr[4];
#pragma unroll
        for (int i = 0; i < 4; ++i) af[i] = *(const bf16x8*)&As[arow + i * 16 * BK];
#pragma unroll
        for (int j = 0; j < 4; ++j) bfr[j] = *(const bf16x8*)&Bs[brow + j * 16 * BK];
#pragma unroll
        for (int i = 0; i < 4; ++i)
#pragma unroll
            for (int j = 0; j < 4; ++j)
                acc[i][j] = __builtin_amdgcn_mfma_f32_16x16x32_bf16(af[i], bfr[j], acc[i][j], 0, 0, 0);
        __syncthreads();
    }

    int r0 = rowBase + wr * 64 + ((lane >> 4) << 2);
    int c0 = wc * 64 + (lane & 15);
#pragma unroll
    for (int j = 0; j < 4; ++j) {
        int col = c0 + j * 16;
        float inv = 1.0f / (ks[col] + 1e-10f);
#pragma unroll
        for (int i = 0; i < 4; ++i) {
            int row = r0 + i * 16;
#pragma unroll
            for (int r = 0; r < 4; ++r) {
                float v = acc[i][j][r] * inv;
                Out[(size_t)(row + r) * HIDDEN + h * HD + col] = f2bf(v);
            }
        }
    }
}

// ---------------------------------------------------------------- launch
extern "C" void kernel_launch(void* const* d_in, const int* in_sizes, int n_in,
                              void* d_out, int out_size, void* d_ws, size_t ws_size,
                              hipStream_t stream)
{
    const float* hs = (const float*)d_in[0];
    const float* Wq = (const float*)d_in[1];
    const float* bq = (const float*)d_in[2];
    const float* Wk = (const float*)d_in[3];
    const float* bk = (const float*)d_in[4];
    const float* Wv = (const float*)d_in[5];
    const float* bv = (const float*)d_in[6];
    const float* Wo = (const float*)d_in[7];
    const float* bo = (const float*)d_in[8];

    char* ws = (char*)d_ws;
    size_t off = 0;
    auto alloc = [&](size_t bytes) -> char* {
        char* p = ws + off;
        off += (bytes + 255) & ~(size_t)255;
        return p;
    };

    unsigned short* hs_b  = (unsigned short*)alloc((size_t)ROWS * HIDDEN * 2);    // 67 MB (reused by attn out)
    unsigned short* Wq_b  = (unsigned short*)alloc((size_t)HIDDEN * HIDDEN * 2);  // 33.5 MB (reused by kvp)
    unsigned short* Wkv_b = (unsigned short*)alloc((size_t)2048 * HIDDEN * 2);    // 16.8 MB (Wk rows 0..1023, Wv rows 1024..2047)
    unsigned short* Wo_b  = (unsigned short*)alloc((size_t)HIDDEN * HIDDEN * 2);  // 33.5 MB
    unsigned short* kvout = (unsigned short*)alloc((size_t)ROWS * 2048 * 2);      // 33.5 MB [row][K(1024)|V(1024)]
    float* ksp   = (float*)alloc((size_t)16 * 32 * HD * 4);
    unsigned short* kvb = (unsigned short*)alloc((size_t)16 * HD * HD * 2);
    float* ksum  = (float*)alloc((size_t)16 * HD * 4);

    // aliases (lifetime-disjoint):
    float* kvp = (float*)Wq_b;                    // Wq dead after Q GEMM
    unsigned short* attn_b = hs_b;                // hs dead after KV GEMM
    unsigned short* q_b = (unsigned short*)d_out; // front 67 MB of d_out, dead before final GEMM writes

    (void)in_sizes; (void)n_in; (void)out_size; (void)ws_size;

    auto cast = [&](const float* in, unsigned short* out, size_t n) {
        int n4 = (int)(n / 4);
        int blocks = (n4 + 255) / 256;
        if (blocks > 2048) blocks = 2048;
        cast_kernel<<<dim3(blocks), dim3(256), 0, stream>>>(in, out, n4);
    };

    cast(hs, hs_b, (size_t)ROWS * HIDDEN);
    cast(Wq, Wq_b, (size_t)HIDDEN * HIDDEN);
    cast(Wk, Wkv_b, (size_t)1024 * HIDDEN);
    cast(Wv, Wkv_b + (size_t)1024 * HIDDEN, (size_t)1024 * HIDDEN);
    cast(Wo, Wo_b, (size_t)HIDDEN * HIDDEN);

    // Q = phi(hs @ Wq^T + bq) -> bf16   [8192 x 4096], 512 wgs
    gemm256<1><<<dim3(512), dim3(512), 0, stream>>>(hs_b, HIDDEN, Wq_b, HIDDEN, bq, nullptr, q_b, ROWS, HIDDEN, HIDDEN);
    // [K|V] fused -> bf16  [8192 x 2048], 256 wgs
    gemm256<2><<<dim3(256), dim3(512), 0, stream>>>(hs_b, HIDDEN, Wkv_b, HIDDEN, bk, bv, kvout, ROWS, 2048, HIDDEN);

    // KV summary + ksum
    kv_partial<<<dim3(32, 16), dim3(256), 0, stream>>>(kvout, kvout + 1024, 2048, kvp, ksp);
    kv_reduce<<<dim3(16, 16), dim3(256), 0, stream>>>(kvp, ksp, kvb, ksum);

    // attn = (q @ kv^T) / (ksum + eps) -> bf16  [8192 x 4096]
    attn_gemm<<<dim3(64, 32), dim3(256), 0, stream>>>(q_b, kvb, ksum, attn_b);

    // out = attn @ Wo^T + bo -> f32
    gemm256<0><<<dim3(512), dim3(512), 0, stream>>>(attn_b, HIDDEN, Wo_b, HIDDEN, bo, nullptr, d_out, ROWS, HIDDEN, HIDDEN);
}